// Round 10
// baseline (497.335 us; speedup 1.0000x reference)
//
#include <hip/hip_runtime.h>

#define NG 512
#define HID 64

// ---------------- degree ----------------
__global__ void deg_kernel(const int* __restrict__ dst, int* __restrict__ deg, int E) {
    int e = blockIdx.x * blockDim.x + threadIdx.x;
    if (e < E) atomicAdd(&deg[dst[e]], 1);
}

// ---------------- CSR build ----------------
__global__ void block_sums_kernel(const int* __restrict__ deg, int* __restrict__ bsum, int N) {
    __shared__ int s[256];
    int i = blockIdx.x * 256 + threadIdx.x;
    s[threadIdx.x] = (i < N) ? deg[i] : 0;
    __syncthreads();
    for (int off = 128; off > 0; off >>= 1) {
        if (threadIdx.x < off) s[threadIdx.x] += s[threadIdx.x + off];
        __syncthreads();
    }
    if (threadIdx.x == 0) bsum[blockIdx.x] = s[0];
}

__global__ __launch_bounds__(1024) void scan_bsum_kernel(const int* __restrict__ bsum,
                                                         int* __restrict__ bofs, int nb) {
    __shared__ int s[1024];
    __shared__ int carry;
    if (threadIdx.x == 0) carry = 0;
    __syncthreads();
    for (int base = 0; base < nb; base += 1024) {
        int i = base + threadIdx.x;
        int v = (i < nb) ? bsum[i] : 0;
        s[threadIdx.x] = v;
        __syncthreads();
        for (int off = 1; off < 1024; off <<= 1) {
            int t = (threadIdx.x >= off) ? s[threadIdx.x - off] : 0;
            __syncthreads();
            s[threadIdx.x] += t;
            __syncthreads();
        }
        if (i < nb) bofs[i] = carry + s[threadIdx.x] - v;  // exclusive
        __syncthreads();
        if (threadIdx.x == 1023) carry += s[1023];
        __syncthreads();
    }
}

__global__ void scan_block_kernel(const int* __restrict__ deg, const int* __restrict__ bofs,
                                  int* __restrict__ rowptr, float* __restrict__ dinv,
                                  int N, int E) {
    __shared__ int tmp[256];
    int i = blockIdx.x * 256 + threadIdx.x;
    int v = (i < N) ? deg[i] : 0;
    tmp[threadIdx.x] = v;
    __syncthreads();
    for (int off = 1; off < 256; off <<= 1) {
        int t = (threadIdx.x >= off) ? tmp[threadIdx.x - off] : 0;
        __syncthreads();
        tmp[threadIdx.x] += t;
        __syncthreads();
    }
    if (i < N) {
        rowptr[i] = bofs[blockIdx.x] + tmp[threadIdx.x] - v;  // exclusive
        dinv[i] = rsqrtf((float)v + 1.0f);
    }
    if (i == 0) rowptr[N] = E;
}

__global__ void bucket_kernel(const int* __restrict__ src, const int* __restrict__ dst,
                              const int* __restrict__ rowptr, int* __restrict__ cur,
                              int* __restrict__ esrc, int E) {
    int e = blockIdx.x * blockDim.x + threadIdx.x;
    if (e >= E) return;
    int d = dst[e];
    int p = rowptr[d] + atomicAdd(&cur[d], 1);
    esrc[p] = src[e];
}

// ---------------- layer 1 (one wave/node, replay-verified) + prescale ----------------
// hs[i] = relu((Ax@W1)[i] + b1) * dinv[i]
// NOTE: R7's 4-node/wave 16-lane-subgroup variant caused 3.4e-3 replay instability.
__global__ void layer1_kernel(const float* __restrict__ x, const int* __restrict__ rowptr,
                              const int* __restrict__ esrc, const float* __restrict__ dinv,
                              const float* __restrict__ W1, const float* __restrict__ b1,
                              float* __restrict__ hs, int N) {
    int t = blockIdx.x * blockDim.x + threadIdx.x;
    int node = t >> 6, lane = t & 63;
    if (node >= N) return;
    const float2* x2 = (const float2*)x;
    int k0 = rowptr[node], k1 = rowptr[node + 1];
    float s0 = 0.0f, s1 = 0.0f;
    for (int base = k0; base < k1; base += 64) {
        int cnt = min(64, k1 - base);
        if (lane < cnt) {
            int s = esrc[base + lane];
            float dv = dinv[s];
            float2 xv = x2[s];
            s0 = fmaf(xv.x, dv, s0);
            s1 = fmaf(xv.y, dv, s1);
        }
    }
#pragma unroll
    for (int m = 32; m > 0; m >>= 1) {
        s0 += __shfl_xor(s0, m);
        s1 += __shfl_xor(s1, m);
    }
    float di = dinv[node];
    float2 xn = x2[node];
    float m0 = (s0 + xn.x * di) * di;  // = di*sum + x*di^2
    float m1 = (s1 + xn.y * di) * di;
    float v = fmaf(m0, W1[lane], fmaf(m1, W1[HID + lane], b1[lane]));
    hs[(size_t)node * HID + lane] = fmaxf(v, 0.0f) * di;  // prescale for layer2
}

// ---------------- layer 2 fully fused: ONE WAVE PER NODE (max TLP) ----------------
// R9 grid-stride (6 nodes/wave serial) was latency-bound at 37% occupancy.
// 1 node/wave: single 3-hop chain per wave; TLP hides latency. LDS 16KB/block
// -> 8 blocks/CU -> 32 waves/CU possible.
__global__ __launch_bounds__(256, 4) void layer2_fused_kernel(
    const int* __restrict__ rowptr, const int* __restrict__ esrc,
    const float* __restrict__ dinv, const float* __restrict__ hs,
    const float* __restrict__ W2, const float* __restrict__ b2,
    const int* __restrict__ batch, float* __restrict__ gsum, int* __restrict__ gcnt, int N) {
    __shared__ float Ws[HID * HID];  // k-major: Ws[k*64+j]
    {
        float4* Ws4 = (float4*)Ws;
        const float4* W24 = (const float4*)W2;
        for (int t = threadIdx.x; t < HID * HID / 4; t += 256) Ws4[t] = W24[t];
    }
    __syncthreads();
    int lane = threadIdx.x & 63;
    int node = (blockIdx.x * 256 + threadIdx.x) >> 6;
    if (node >= N) return;
    int fl = lane & 15;       // feature-quad
    int eo = lane >> 4;       // edge slot
    const float4* h4 = (const float4*)hs;
    int k0 = rowptr[node];
    int k1 = rowptr[node + 1];
    float di = dinv[node];
    float4 self = h4[(size_t)node * 16 + fl];
    float ax = 0.f, ay = 0.f, az = 0.f, aw = 0.f;
    for (int base = k0; base < k1; base += 64) {
        int cnt = min(64, k1 - base);
        int sv = esrc[base + min(lane, cnt - 1)];  // one coalesced chunk load
        for (int i0 = 0; i0 < cnt; i0 += 16) {
            int e0 = i0 + eo, e1 = i0 + 4 + eo, e2 = i0 + 8 + eo, e3 = i0 + 12 + eo;
            int s0 = __shfl(sv, e0), s1 = __shfl(sv, e1);
            int s2 = __shfl(sv, e2), s3 = __shfl(sv, e3);
            float w0 = (e0 < cnt) ? 1.f : 0.f;
            float w1 = (e1 < cnt) ? 1.f : 0.f;
            float w2 = (e2 < cnt) ? 1.f : 0.f;
            float w3 = (e3 < cnt) ? 1.f : 0.f;
            if (e0 >= cnt) s0 = node;
            if (e1 >= cnt) s1 = node;
            if (e2 >= cnt) s2 = node;
            if (e3 >= cnt) s3 = node;
            float4 r0 = h4[(size_t)s0 * 16 + fl];  // 4 independent dwordx4 loads
            float4 r1 = h4[(size_t)s1 * 16 + fl];
            float4 r2 = h4[(size_t)s2 * 16 + fl];
            float4 r3 = h4[(size_t)s3 * 16 + fl];
            ax = fmaf(r0.x, w0, ax); ay = fmaf(r0.y, w0, ay);
            az = fmaf(r0.z, w0, az); aw = fmaf(r0.w, w0, aw);
            ax = fmaf(r1.x, w1, ax); ay = fmaf(r1.y, w1, ay);
            az = fmaf(r1.z, w1, az); aw = fmaf(r1.w, w1, aw);
            ax = fmaf(r2.x, w2, ax); ay = fmaf(r2.y, w2, ay);
            az = fmaf(r2.z, w2, az); aw = fmaf(r2.w, w2, aw);
            ax = fmaf(r3.x, w3, ax); ay = fmaf(r3.y, w3, ay);
            az = fmaf(r3.z, w3, az); aw = fmaf(r3.w, w3, aw);
        }
    }
    // reduce across the 4 eo-groups (fl preserved by xor 16/32)
    ax += __shfl_xor(ax, 16); ay += __shfl_xor(ay, 16);
    az += __shfl_xor(az, 16); aw += __shfl_xor(aw, 16);
    ax += __shfl_xor(ax, 32); ay += __shfl_xor(ay, 32);
    az += __shfl_xor(az, 32); aw += __shfl_xor(aw, 32);
    float a0 = (ax + self.x) * di;
    float a1 = (ay + self.y) * di;
    float a2 = (az + self.z) * di;
    float a3 = (aw + self.w) * di;
    // matvec: z[lane] = b2 + sum_k agg[k]*W2[k][lane]; agg[q*4+c] at lane q, comp c
    float z = b2[lane];
#pragma unroll
    for (int q = 0; q < 16; ++q) {
        z = fmaf(__shfl(a0, q), Ws[(q * 4 + 0) * HID + lane], z);
        z = fmaf(__shfl(a1, q), Ws[(q * 4 + 1) * HID + lane], z);
        z = fmaf(__shfl(a2, q), Ws[(q * 4 + 2) * HID + lane], z);
        z = fmaf(__shfl(a3, q), Ws[(q * 4 + 3) * HID + lane], z);
    }
    z = fmaxf(z, 0.0f);
    int g = batch[node];
    atomicAdd(&gsum[g * HID + lane], z);
    if (lane == 0) atomicAdd(&gcnt[g], 1);
}

// ---------------- head ----------------
__global__ void head_kernel(const float* __restrict__ gsum, const int* __restrict__ gcnt,
                            const float* __restrict__ Wf1, const float* __restrict__ bf1,
                            const float* __restrict__ Wf2, const float* __restrict__ bf2,
                            float* __restrict__ out) {
    __shared__ float gs[HID];
    __shared__ float ts[HID];
    int b = blockIdx.x;
    int j = threadIdx.x;
    float cnt = fmaxf((float)gcnt[b], 1.0f);
    gs[j] = gsum[b * HID + j] / cnt;
    __syncthreads();
    float acc = bf1[j];
#pragma unroll
    for (int k = 0; k < HID; ++k) acc = fmaf(gs[k], Wf1[k * HID + j], acc);
    ts[j] = fmaxf(acc, 0.0f);
    __syncthreads();
    if (j < 4) {
        float o = bf2[j];
#pragma unroll
        for (int k = 0; k < HID; ++k) o = fmaf(ts[k], Wf2[k * 4 + j], o);
        out[b * 4 + j] = o;
    }
}

extern "C" void kernel_launch(void* const* d_in, const int* in_sizes, int n_in,
                              void* d_out, int out_size, void* d_ws, size_t ws_size,
                              hipStream_t stream) {
    const float* x   = (const float*)d_in[0];
    const int*   ei  = (const int*)d_in[1];
    const int*   bat = (const int*)d_in[2];
    const float* W1  = (const float*)d_in[4];
    const float* b1  = (const float*)d_in[5];
    const float* W2  = (const float*)d_in[6];
    const float* b2  = (const float*)d_in[7];
    const float* Wf1 = (const float*)d_in[8];
    const float* bf1 = (const float*)d_in[9];
    const float* Wf2 = (const float*)d_in[10];
    const float* bf2 = (const float*)d_in[11];
    float* out = (float*)d_out;

    int N = in_sizes[2];
    int E = in_sizes[1] / 2;
    const int* src = ei;
    const int* dst = ei + E;
    int nb = (N + 255) / 256;

    char* ws = (char*)d_ws;
    size_t off = 0;
    auto alloc = [&](size_t bytes) {
        char* p = ws + off;
        off = (off + bytes + 255) & ~(size_t)255;
        return p;
    };
    int*   deg    = (int*)alloc((size_t)N * 4);
    int*   cur    = (int*)alloc((size_t)N * 4);
    float* dinv   = (float*)alloc((size_t)N * 4);
    int*   rowptr = (int*)alloc((size_t)(N + 1) * 4);
    int*   bsum   = (int*)alloc((size_t)nb * 4);
    int*   bofs   = (int*)alloc((size_t)nb * 4);
    int*   esrc   = (int*)alloc((size_t)E * 4);
    float* hbuf   = (float*)alloc((size_t)N * HID * 4);
    float* gsum   = (float*)alloc((size_t)NG * HID * 4);
    int*   gcnt   = (int*)alloc((size_t)NG * 4);

    hipMemsetAsync(deg, 0, (size_t)((char*)cur - (char*)deg) + (size_t)N * 4, stream);
    hipMemsetAsync(gsum, 0, (size_t)((char*)gcnt - (char*)gsum) + (size_t)NG * 4, stream);

    int nh = N * HID;

    deg_kernel<<<(E + 255) / 256, 256, 0, stream>>>(dst, deg, E);
    block_sums_kernel<<<nb, 256, 0, stream>>>(deg, bsum, N);
    scan_bsum_kernel<<<1, 1024, 0, stream>>>(bsum, bofs, nb);
    scan_block_kernel<<<nb, 256, 0, stream>>>(deg, bofs, rowptr, dinv, N, E);
    bucket_kernel<<<(E + 255) / 256, 256, 0, stream>>>(src, dst, rowptr, cur, esrc, E);

    // layer 1 (one wave/node), writes prescaled hs = h1*dinv
    layer1_kernel<<<(nh + 255) / 256, 256, 0, stream>>>(x, rowptr, esrc, dinv, W1, b1, hbuf, N);

    // layer 2 fully fused, one wave per node: gather hs -> @W2 -> relu -> pool
    layer2_fused_kernel<<<(nh + 255) / 256, 256, 0, stream>>>(rowptr, esrc, dinv, hbuf, W2, b2,
                                                              bat, gsum, gcnt, N);

    head_kernel<<<NG, HID, 0, stream>>>(gsum, gcnt, Wf1, bf1, Wf2, bf2, out);
}

// Round 11
// 403.764 us; speedup vs baseline: 1.2317x; 1.2317x over previous
//
#include <hip/hip_runtime.h>

#define NG 512
#define HID 64

// ---------------- degree ----------------
__global__ void deg_kernel(const int* __restrict__ dst, int* __restrict__ deg, int E) {
    int e = blockIdx.x * blockDim.x + threadIdx.x;
    if (e < E) atomicAdd(&deg[dst[e]], 1);
}

// ---------------- CSR build ----------------
__global__ void block_sums_kernel(const int* __restrict__ deg, int* __restrict__ bsum, int N) {
    __shared__ int s[256];
    int i = blockIdx.x * 256 + threadIdx.x;
    s[threadIdx.x] = (i < N) ? deg[i] : 0;
    __syncthreads();
    for (int off = 128; off > 0; off >>= 1) {
        if (threadIdx.x < off) s[threadIdx.x] += s[threadIdx.x + off];
        __syncthreads();
    }
    if (threadIdx.x == 0) bsum[blockIdx.x] = s[0];
}

__global__ __launch_bounds__(1024) void scan_bsum_kernel(const int* __restrict__ bsum,
                                                         int* __restrict__ bofs, int nb) {
    __shared__ int s[1024];
    __shared__ int carry;
    if (threadIdx.x == 0) carry = 0;
    __syncthreads();
    for (int base = 0; base < nb; base += 1024) {
        int i = base + threadIdx.x;
        int v = (i < nb) ? bsum[i] : 0;
        s[threadIdx.x] = v;
        __syncthreads();
        for (int off = 1; off < 1024; off <<= 1) {
            int t = (threadIdx.x >= off) ? s[threadIdx.x - off] : 0;
            __syncthreads();
            s[threadIdx.x] += t;
            __syncthreads();
        }
        if (i < nb) bofs[i] = carry + s[threadIdx.x] - v;  // exclusive
        __syncthreads();
        if (threadIdx.x == 1023) carry += s[1023];
        __syncthreads();
    }
}

__global__ void scan_block_kernel(const int* __restrict__ deg, const int* __restrict__ bofs,
                                  int* __restrict__ rowptr, float* __restrict__ dinv,
                                  int N, int E) {
    __shared__ int tmp[256];
    int i = blockIdx.x * 256 + threadIdx.x;
    int v = (i < N) ? deg[i] : 0;
    tmp[threadIdx.x] = v;
    __syncthreads();
    for (int off = 1; off < 256; off <<= 1) {
        int t = (threadIdx.x >= off) ? tmp[threadIdx.x - off] : 0;
        __syncthreads();
        tmp[threadIdx.x] += t;
        __syncthreads();
    }
    if (i < N) {
        rowptr[i] = bofs[blockIdx.x] + tmp[threadIdx.x] - v;  // exclusive
        dinv[i] = rsqrtf((float)v + 1.0f);
    }
    if (i == 0) rowptr[N] = E;
}

// bucket + layer1 input staging: xsc[p] = x[src]*dinv[src] (CSR-ordered, so layer1
// reads it COALESCED). Edge-level TLP hides the scattered x/dinv gathers here,
// where the wave-per-node layer1 could not.
__global__ void bucket_kernel(const int* __restrict__ src, const int* __restrict__ dst,
                              const int* __restrict__ rowptr, int* __restrict__ cur,
                              int* __restrict__ esrc, const float* __restrict__ x,
                              const float* __restrict__ dinv, float2* __restrict__ xsc, int E) {
    int e = blockIdx.x * blockDim.x + threadIdx.x;
    if (e >= E) return;
    int s = src[e];
    int d = dst[e];
    int p = rowptr[d] + atomicAdd(&cur[d], 1);
    esrc[p] = s;
    const float2* x2 = (const float2*)x;
    float dv = dinv[s];
    float2 xv = x2[s];
    xsc[p] = make_float2(xv.x * dv, xv.y * dv);
}

// ---------------- layer 1 (one wave/node, replay-verified shape) ----------------
// hs[i] = relu((Ax@W1)[i] + b1) * dinv[i]; neighbor term now a COALESCED sum of xsc.
// NOTE: R7's 16-lane-subgroup variant caused 3.4e-3 replay instability — keep 64-lane.
__global__ void layer1_kernel(const float* __restrict__ x, const int* __restrict__ rowptr,
                              const float2* __restrict__ xsc, const float* __restrict__ dinv,
                              const float* __restrict__ W1, const float* __restrict__ b1,
                              float* __restrict__ hs, int N) {
    int t = blockIdx.x * blockDim.x + threadIdx.x;
    int node = t >> 6, lane = t & 63;
    if (node >= N) return;
    const float2* x2 = (const float2*)x;
    int k0 = rowptr[node], k1 = rowptr[node + 1];
    float s0 = 0.0f, s1 = 0.0f;
    for (int k = k0 + lane; k < k1; k += 64) {
        float2 v = xsc[k];            // coalesced, prescaled
        s0 += v.x;
        s1 += v.y;
    }
#pragma unroll
    for (int m = 32; m > 0; m >>= 1) {
        s0 += __shfl_xor(s0, m);
        s1 += __shfl_xor(s1, m);
    }
    float di = dinv[node];
    float2 xn = x2[node];
    float m0 = (s0 + xn.x * di) * di;  // = di*sum + x*di^2
    float m1 = (s1 + xn.y * di) * di;
    float v = fmaf(m0, W1[lane], fmaf(m1, W1[HID + lane], b1[lane]));
    hs[(size_t)node * HID + lane] = fmaxf(v, 0.0f) * di;  // prescale for layer2
}

// ---------------- layer 2 fully fused, grid-stride + software pipeline ----------------
// R9 grid-stride = best base (187us; R10 1-node/wave regressed: VGPR 32 shrank MLP,
// W2 staging unamortized). Pipeline: prefetch next node's rowptr during gathers,
// next esrc chunk + self row during the epilogue matvec.
// (256,4): 64-VGPR cap, no spill (R5/R9). (256,8)->32 spilled (R4); 76 -> occ cliff (R6).
__global__ __launch_bounds__(256, 4) void layer2_fused_kernel(
    const int* __restrict__ rowptr, const int* __restrict__ esrc,
    const float* __restrict__ dinv, const float* __restrict__ hs,
    const float* __restrict__ W2, const float* __restrict__ b2,
    const int* __restrict__ batch, float* __restrict__ gsum, int* __restrict__ gcnt, int N) {
    __shared__ float Ws[HID * HID];  // k-major: Ws[k*64+j]
    {
        float4* Ws4 = (float4*)Ws;
        const float4* W24 = (const float4*)W2;
        for (int t = threadIdx.x; t < HID * HID / 4; t += 256) Ws4[t] = W24[t];
    }
    __syncthreads();
    int lane = threadIdx.x & 63;
    int fl = lane & 15;       // feature-quad
    int eo = lane >> 4;       // edge slot
    float bz = b2[lane];
    const float4* h4 = (const float4*)hs;
    int wave = (blockIdx.x * 256 + threadIdx.x) >> 6;
    int nwaves = gridDim.x * 4;

    int node = wave;
    int k0 = 0, k1 = 0, sv = 0;
    float4 self = make_float4(0.f, 0.f, 0.f, 0.f);
    if (node < N) {
        k0 = rowptr[node];
        k1 = rowptr[node + 1];
        int cnt = min(64, k1 - k0);
        sv = esrc[k0 + min(lane, cnt - 1)];
        self = h4[(size_t)node * 16 + fl];
    }
    while (node < N) {
        int next = node + nwaves;
        int k0n = 0, k1n = 0;
        if (next < N) { k0n = rowptr[next]; k1n = rowptr[next + 1]; }  // prefetch hop A
        float di = dinv[node];
        int cnt = min(64, k1 - k0);
        float ax = 0.f, ay = 0.f, az = 0.f, aw = 0.f;
        // chunk 1: sv already in flight from previous iteration's prefetch
        for (int i0 = 0; i0 < cnt; i0 += 16) {
            int e0 = i0 + eo, e1 = i0 + 4 + eo, e2 = i0 + 8 + eo, e3 = i0 + 12 + eo;
            int s0 = __shfl(sv, e0), s1 = __shfl(sv, e1);
            int s2 = __shfl(sv, e2), s3 = __shfl(sv, e3);
            float w0 = (e0 < cnt) ? 1.f : 0.f;
            float w1 = (e1 < cnt) ? 1.f : 0.f;
            float w2 = (e2 < cnt) ? 1.f : 0.f;
            float w3 = (e3 < cnt) ? 1.f : 0.f;
            if (e0 >= cnt) s0 = node;
            if (e1 >= cnt) s1 = node;
            if (e2 >= cnt) s2 = node;
            if (e3 >= cnt) s3 = node;
            float4 r0 = h4[(size_t)s0 * 16 + fl];
            float4 r1 = h4[(size_t)s1 * 16 + fl];
            float4 r2 = h4[(size_t)s2 * 16 + fl];
            float4 r3 = h4[(size_t)s3 * 16 + fl];
            ax = fmaf(r0.x, w0, ax); ay = fmaf(r0.y, w0, ay);
            az = fmaf(r0.z, w0, az); aw = fmaf(r0.w, w0, aw);
            ax = fmaf(r1.x, w1, ax); ay = fmaf(r1.y, w1, ay);
            az = fmaf(r1.z, w1, az); aw = fmaf(r1.w, w1, aw);
            ax = fmaf(r2.x, w2, ax); ay = fmaf(r2.y, w2, ay);
            az = fmaf(r2.z, w2, az); aw = fmaf(r2.w, w2, aw);
            ax = fmaf(r3.x, w3, ax); ay = fmaf(r3.y, w3, ay);
            az = fmaf(r3.z, w3, az); aw = fmaf(r3.w, w3, aw);
        }
        // rare deg>64 tail chunks
        for (int base = k0 + 64; base < k1; base += 64) {
            int c2 = min(64, k1 - base);
            int sv2 = esrc[base + min(lane, c2 - 1)];
            for (int i0 = 0; i0 < c2; i0 += 16) {
                int e0 = i0 + eo, e1 = i0 + 4 + eo, e2 = i0 + 8 + eo, e3 = i0 + 12 + eo;
                int s0 = __shfl(sv2, e0), s1 = __shfl(sv2, e1);
                int s2 = __shfl(sv2, e2), s3 = __shfl(sv2, e3);
                float w0 = (e0 < c2) ? 1.f : 0.f;
                float w1 = (e1 < c2) ? 1.f : 0.f;
                float w2 = (e2 < c2) ? 1.f : 0.f;
                float w3 = (e3 < c2) ? 1.f : 0.f;
                if (e0 >= c2) s0 = node;
                if (e1 >= c2) s1 = node;
                if (e2 >= c2) s2 = node;
                if (e3 >= c2) s3 = node;
                float4 r0 = h4[(size_t)s0 * 16 + fl];
                float4 r1 = h4[(size_t)s1 * 16 + fl];
                float4 r2 = h4[(size_t)s2 * 16 + fl];
                float4 r3 = h4[(size_t)s3 * 16 + fl];
                ax = fmaf(r0.x, w0, ax); ay = fmaf(r0.y, w0, ay);
                az = fmaf(r0.z, w0, az); aw = fmaf(r0.w, w0, aw);
                ax = fmaf(r1.x, w1, ax); ay = fmaf(r1.y, w1, ay);
                az = fmaf(r1.z, w1, az); aw = fmaf(r1.w, w1, aw);
                ax = fmaf(r2.x, w2, ax); ay = fmaf(r2.y, w2, ay);
                az = fmaf(r2.z, w2, az); aw = fmaf(r2.w, w2, aw);
                ax = fmaf(r3.x, w3, ax); ay = fmaf(r3.y, w3, ay);
                az = fmaf(r3.z, w3, az); aw = fmaf(r3.w, w3, aw);
            }
        }
        // prefetch hop B: next node's first esrc chunk + self row, hidden by epilogue
        int svn = 0;
        float4 selfn = make_float4(0.f, 0.f, 0.f, 0.f);
        if (next < N) {
            int cn = min(64, k1n - k0n);
            svn = esrc[k0n + min(lane, cn - 1)];
            selfn = h4[(size_t)next * 16 + fl];
        }
        // epilogue: eo-reduce + matvec + pool
        ax += __shfl_xor(ax, 16); ay += __shfl_xor(ay, 16);
        az += __shfl_xor(az, 16); aw += __shfl_xor(aw, 16);
        ax += __shfl_xor(ax, 32); ay += __shfl_xor(ay, 32);
        az += __shfl_xor(az, 32); aw += __shfl_xor(aw, 32);
        float a0 = (ax + self.x) * di;
        float a1 = (ay + self.y) * di;
        float a2 = (az + self.z) * di;
        float a3 = (aw + self.w) * di;
        float z = bz;
#pragma unroll
        for (int q = 0; q < 16; ++q) {
            z = fmaf(__shfl(a0, q), Ws[(q * 4 + 0) * HID + lane], z);
            z = fmaf(__shfl(a1, q), Ws[(q * 4 + 1) * HID + lane], z);
            z = fmaf(__shfl(a2, q), Ws[(q * 4 + 2) * HID + lane], z);
            z = fmaf(__shfl(a3, q), Ws[(q * 4 + 3) * HID + lane], z);
        }
        z = fmaxf(z, 0.0f);
        int g = batch[node];
        atomicAdd(&gsum[g * HID + lane], z);
        if (lane == 0) atomicAdd(&gcnt[g], 1);
        node = next; k0 = k0n; k1 = k1n; sv = svn; self = selfn;
    }
}

// ---------------- head ----------------
__global__ void head_kernel(const float* __restrict__ gsum, const int* __restrict__ gcnt,
                            const float* __restrict__ Wf1, const float* __restrict__ bf1,
                            const float* __restrict__ Wf2, const float* __restrict__ bf2,
                            float* __restrict__ out) {
    __shared__ float gs[HID];
    __shared__ float ts[HID];
    int b = blockIdx.x;
    int j = threadIdx.x;
    float cnt = fmaxf((float)gcnt[b], 1.0f);
    gs[j] = gsum[b * HID + j] / cnt;
    __syncthreads();
    float acc = bf1[j];
#pragma unroll
    for (int k = 0; k < HID; ++k) acc = fmaf(gs[k], Wf1[k * HID + j], acc);
    ts[j] = fmaxf(acc, 0.0f);
    __syncthreads();
    if (j < 4) {
        float o = bf2[j];
#pragma unroll
        for (int k = 0; k < HID; ++k) o = fmaf(ts[k], Wf2[k * 4 + j], o);
        out[b * 4 + j] = o;
    }
}

extern "C" void kernel_launch(void* const* d_in, const int* in_sizes, int n_in,
                              void* d_out, int out_size, void* d_ws, size_t ws_size,
                              hipStream_t stream) {
    const float* x   = (const float*)d_in[0];
    const int*   ei  = (const int*)d_in[1];
    const int*   bat = (const int*)d_in[2];
    const float* W1  = (const float*)d_in[4];
    const float* b1  = (const float*)d_in[5];
    const float* W2  = (const float*)d_in[6];
    const float* b2  = (const float*)d_in[7];
    const float* Wf1 = (const float*)d_in[8];
    const float* bf1 = (const float*)d_in[9];
    const float* Wf2 = (const float*)d_in[10];
    const float* bf2 = (const float*)d_in[11];
    float* out = (float*)d_out;

    int N = in_sizes[2];
    int E = in_sizes[1] / 2;
    const int* src = ei;
    const int* dst = ei + E;
    int nb = (N + 255) / 256;

    char* ws = (char*)d_ws;
    size_t off = 0;
    auto alloc = [&](size_t bytes) {
        char* p = ws + off;
        off = (off + bytes + 255) & ~(size_t)255;
        return p;
    };
    int*    deg    = (int*)alloc((size_t)N * 4);
    int*    cur    = (int*)alloc((size_t)N * 4);
    float*  dinv   = (float*)alloc((size_t)N * 4);
    int*    rowptr = (int*)alloc((size_t)(N + 1) * 4);
    int*    bsum   = (int*)alloc((size_t)nb * 4);
    int*    bofs   = (int*)alloc((size_t)nb * 4);
    int*    esrc   = (int*)alloc((size_t)E * 4);
    float2* xsc    = (float2*)alloc((size_t)E * 8);
    float*  hbuf   = (float*)alloc((size_t)N * HID * 4);
    float*  gsum   = (float*)alloc((size_t)NG * HID * 4);
    int*    gcnt   = (int*)alloc((size_t)NG * 4);

    hipMemsetAsync(deg, 0, (size_t)((char*)cur - (char*)deg) + (size_t)N * 4, stream);
    hipMemsetAsync(gsum, 0, (size_t)((char*)gcnt - (char*)gsum) + (size_t)NG * 4, stream);

    int nh = N * HID;

    deg_kernel<<<(E + 255) / 256, 256, 0, stream>>>(dst, deg, E);
    block_sums_kernel<<<nb, 256, 0, stream>>>(deg, bsum, N);
    scan_bsum_kernel<<<1, 1024, 0, stream>>>(bsum, bofs, nb);
    scan_block_kernel<<<nb, 256, 0, stream>>>(deg, bofs, rowptr, dinv, N, E);

    // bucket + layer1 input staging (xsc = x[src]*dinv[src] in CSR order)
    bucket_kernel<<<(E + 255) / 256, 256, 0, stream>>>(src, dst, rowptr, cur, esrc,
                                                       x, dinv, xsc, E);

    // layer 1: coalesced xsc sum -> W1 matvec -> relu -> prescale
    layer1_kernel<<<(nh + 255) / 256, 256, 0, stream>>>(x, rowptr, xsc, dinv, W1, b1, hbuf, N);

    // layer 2 fully fused, pipelined grid-stride
    layer2_fused_kernel<<<4096, 256, 0, stream>>>(rowptr, esrc, dinv, hbuf, W2, b2, bat,
                                                  gsum, gcnt, N);

    head_kernel<<<NG, HID, 0, stream>>>(gsum, gcnt, Wf1, bf1, Wf2, bf2, out);
}